// Round 7
// baseline (360.504 us; speedup 1.0000x reference)
//
#include <hip/hip_runtime.h>

// SelfAttention (SAGAN-style), B=4, C=256, N=4096, Dqk=32.
// Round 7: attn occupancy fix — 512 blocks x 32q (P tile 33KB -> 2 blocks/CU,
// 4 waves/SIMD). Phase A: 8 waves x 64-key stripes -> shared P LDS.
// Phase B: wave = (16q half, 64ch group), V double-buffered, static indices.
// VGPR engineered <= 128 for launch_bounds(512,4). proj unchanged.

#define BATCH 4
#define CH    256
#define NPIX  4096
#define DQKD  32

typedef __attribute__((ext_vector_type(8))) short bf16x8;
typedef __attribute__((ext_vector_type(4))) float f32x4;

__device__ __forceinline__ unsigned pk2(float a, float b) {
    return (__float_as_uint(a) >> 16) | (__float_as_uint(b) & 0xffff0000u);
}

// ---------------- projection: q = (Wq x + bq)*log2e, k = Wk x + bk, v = Wv x + bv
__global__ __launch_bounds__(256) void proj_kernel(
    const float* __restrict__ x,
    const float* __restrict__ Wq, const float* __restrict__ bq,
    const float* __restrict__ Wk, const float* __restrict__ bk,
    const float* __restrict__ Wv, const float* __restrict__ bv,
    ushort* __restrict__ qb, ushort* __restrict__ kb, ushort* __restrict__ vb)
{
    __shared__ float w_lds[32][256];
    __shared__ float b_lds[32];
    const int tid = threadIdx.x;
    const int n0  = blockIdx.x * 256;
    const int dt  = blockIdx.y;        // 0:Q, 1:K, 2..9:V rows (dt-2)*32
    const int b   = blockIdx.z;

    const float* W; const float* bias;
    if (dt == 0)      { W = Wq;                              bias = bq; }
    else if (dt == 1) { W = Wk;                              bias = bk; }
    else              { W = Wv + (size_t)(dt - 2) * 32 * CH; bias = bv + (dt - 2) * 32; }

    {
        const float4* w4 = (const float4*)W;
        float4* l4 = (float4*)&w_lds[0][0];
        #pragma unroll
        for (int i = 0; i < 8; ++i) l4[tid + 256 * i] = w4[tid + 256 * i];
        if (tid < 32) b_lds[tid] = bias[tid];
    }
    __syncthreads();

    const int tn = tid & 63;
    const int td = tid >> 6;
    const int n  = n0 + tn * 4;

    float acc[8][4];
    #pragma unroll
    for (int i = 0; i < 8; ++i) {
        float bb = b_lds[td * 8 + i];
        #pragma unroll
        for (int j = 0; j < 4; ++j) acc[i][j] = bb;
    }

    const float* xb = x + (size_t)b * CH * NPIX + n;
    for (int c0 = 0; c0 < CH; c0 += 8) {
        float xr[8][4];
        #pragma unroll
        for (int cc = 0; cc < 8; ++cc) {
            float4 xv = *(const float4*)(xb + (size_t)(c0 + cc) * NPIX);
            xr[cc][0] = xv.x; xr[cc][1] = xv.y; xr[cc][2] = xv.z; xr[cc][3] = xv.w;
        }
        #pragma unroll
        for (int i = 0; i < 8; ++i) {
            #pragma unroll
            for (int h = 0; h < 2; ++h) {
                float4 w4 = *(const float4*)&w_lds[td * 8 + i][c0 + 4 * h];
                float wr[4] = {w4.x, w4.y, w4.z, w4.w};
                #pragma unroll
                for (int cc = 0; cc < 4; ++cc)
                    #pragma unroll
                    for (int j = 0; j < 4; ++j)
                        acc[i][j] = fmaf(wr[cc], xr[4 * h + cc][j], acc[i][j]);
            }
        }
    }

    if (dt == 0 || dt == 1) {          // Q/K layout [b][n][32] bf16
        ushort* dst = (dt == 0) ? qb : kb;
        const float sc = (dt == 0) ? 1.4426950408889634f : 1.0f;  // Q *= log2(e)
        #pragma unroll
        for (int j = 0; j < 4; ++j) {
            uint4 u;
            u.x = pk2(acc[0][j] * sc, acc[1][j] * sc);
            u.y = pk2(acc[2][j] * sc, acc[3][j] * sc);
            u.z = pk2(acc[4][j] * sc, acc[5][j] * sc);
            u.w = pk2(acc[6][j] * sc, acc[7][j] * sc);
            *(uint4*)(dst + ((size_t)b * NPIX + n + j) * DQKD + td * 8) = u;
        }
    } else {                           // V layout [b][c][n] bf16
        const int cbase = (dt - 2) * 32 + td * 8;
        #pragma unroll
        for (int i = 0; i < 8; ++i) {
            uint2 u;
            u.x = pk2(acc[i][0], acc[i][1]);
            u.y = pk2(acc[i][2], acc[i][3]);
            *(uint2*)(vb + ((size_t)b * CH + cbase + i) * NPIX + n) = u;
        }
    }
}

// ---------------- fused flash attention + residual ---------------------------
// 512 blocks x 512 thr. Block: 32 queries x 256 channels, batch-pinned XCD.
// Outer: 512-key tiles. Phase A: wave w -> keys [64w,64w+64) x 32q into P LDS.
// Phase B: wave (qh=w>>2, cg=w&3) -> 16q x 64ch PV over 512 keys.
__global__ __launch_bounds__(512, 4) void attn_kernel(
    const ushort* __restrict__ Qb, const ushort* __restrict__ Kb,
    const ushort* __restrict__ Vb, const float* __restrict__ x,
    const float* __restrict__ gamma_p, float* __restrict__ out)
{
    __shared__ char  p_lds[32 * 1024];     // P[32 q][512 k] bf16, pitch 1024B
    __shared__ float l_lds[8][32];
    __shared__ float linv_lds[32];

    const int tid  = threadIdx.x;
    const int lane = tid & 63;
    const int wv   = tid >> 6;             // 0..7
    const int l15  = lane & 15, g = lane >> 4;
    const unsigned swz = (unsigned)(l15 & 7) << 4;

    int bid  = blockIdx.x;
    int xcd  = bid & 7, slot = bid >> 3;   // 64 blocks per XCD
    int b    = xcd >> 1;                   // batch pinned to XCD pair
    int qt   = slot + 64 * (xcd & 1);      // 0..127
    const int m0 = qt * 32;

    // Q fragments: 2 x 16-query tiles (B-operand)
    bf16x8 qf[2];
    #pragma unroll
    for (int qc = 0; qc < 2; ++qc)
        qf[qc] = *(const bf16x8*)(Qb + ((size_t)b * NPIX + m0 + 16 * qc + l15) * DQKD + 8 * g);

    const ushort* kbase = Kb + ((size_t)b * NPIX + 64 * wv + l15) * DQKD + 8 * g;

    const int qh = wv >> 2;                // 0..1: rows 16*qh..+15
    const int cg = wv & 3;                 // 0..3: ch 64*cg..+63
    const ushort* vbase = Vb + ((size_t)(b * CH + 64 * cg) + l15) * NPIX + 8 * g;

    f32x4 acc[4];
    #pragma unroll
    for (int ct = 0; ct < 4; ++ct) acc[ct] = (f32x4){0.f, 0.f, 0.f, 0.f};
    float l_run[2] = {0.f, 0.f};

    const f32x4 z4 = {0.f, 0.f, 0.f, 0.f};

    #pragma unroll 1
    for (int kt = 0; kt < NPIX; kt += 512) {
        // ---- Phase A: QK^T + exp2 + P write (own 64-key stripe, 32 q) ----
        {
            bf16x8 kf[4];
            #pragma unroll
            for (int t = 0; t < 4; ++t)
                kf[t] = *(const bf16x8*)(kbase + (size_t)(kt + 16 * t) * DQKD);
            #pragma unroll
            for (int t = 0; t < 4; ++t) {
                #pragma unroll
                for (int qc = 0; qc < 2; ++qc) {
                    f32x4 st = __builtin_amdgcn_mfma_f32_16x16x32_bf16(kf[t], qf[qc], z4, 0, 0, 0);
                    float p0 = exp2f(st[0]);
                    float p1 = exp2f(st[1]);
                    float p2 = exp2f(st[2]);
                    float p3 = exp2f(st[3]);
                    l_run[qc] += (p0 + p1) + (p2 + p3);
                    unsigned row = 16 * qc + l15;
                    unsigned off = row * 1024 + ((128u * wv + 32u * t + 8u * g) ^ swz);
                    uint2 u; u.x = pk2(p0, p1); u.y = pk2(p2, p3);
                    *(uint2*)(p_lds + off) = u;
                }
            }
        }
        __syncthreads();

        // ---- Phase B: PV over 512 keys, 16q x 64ch per wave, V dbuf ----
        {
            bf16x8 va[4], vn[4];
            #pragma unroll
            for (int ct = 0; ct < 4; ++ct)
                va[ct] = *(const bf16x8*)(vbase + (size_t)(16 * ct) * NPIX + kt);

#define PV_STEP(CUR, NXT, KS)                                                   \
            {                                                                   \
                if ((KS) < 15) {                                                \
                    _Pragma("unroll")                                           \
                    for (int ct = 0; ct < 4; ++ct)                              \
                        NXT[ct] = *(const bf16x8*)(vbase + (size_t)(16 * ct) * NPIX \
                                                   + kt + 32 * ((KS) + 1));     \
                }                                                               \
                unsigned off = (16u * qh + l15) * 1024u + ((64u * (KS) + 16u * g) ^ swz); \
                bf16x8 pa = *(const bf16x8*)(p_lds + off);                      \
                _Pragma("unroll")                                               \
                for (int ct = 0; ct < 4; ++ct)                                  \
                    acc[ct] = __builtin_amdgcn_mfma_f32_16x16x32_bf16(          \
                        pa, CUR[ct], acc[ct], 0, 0, 0);                         \
            }

            #pragma unroll
            for (int ks2 = 0; ks2 < 8; ++ks2) {
                PV_STEP(va, vn, 2 * ks2);
                PV_STEP(vn, va, 2 * ks2 + 1);
            }
#undef PV_STEP
        }
        __syncthreads();
    }

    // ---- l reduction: per-wave partials -> block totals ----
    #pragma unroll
    for (int qc = 0; qc < 2; ++qc) {
        l_run[qc] += __shfl_xor(l_run[qc], 16);
        l_run[qc] += __shfl_xor(l_run[qc], 32);
        if (g == 0) l_lds[wv][16 * qc + l15] = l_run[qc];
    }
    __syncthreads();
    if (tid < 32) {
        float s = 0.f;
        #pragma unroll
        for (int w = 0; w < 8; ++w) s += l_lds[w][tid];
        linv_lds[tid] = 1.0f / s;
    }
    __syncthreads();

    // ---- epilogue: out = gamma*(acc/l) + x ----
    const float gm = gamma_p[0];
    float4 li = *(const float4*)&linv_lds[16 * qh + 4 * g];
    #pragma unroll
    for (int ct = 0; ct < 4; ++ct) {
        size_t o = ((size_t)b * CH + 64 * cg + 16 * ct + l15) * NPIX
                 + m0 + 16 * qh + 4 * g;
        float4 xv = *(const float4*)(x + o);
        float4 ov;
        ov.x = fmaf(gm, acc[ct][0] * li.x, xv.x);
        ov.y = fmaf(gm, acc[ct][1] * li.y, xv.y);
        ov.z = fmaf(gm, acc[ct][2] * li.z, xv.z);
        ov.w = fmaf(gm, acc[ct][3] * li.w, xv.w);
        *(float4*)(out + o) = ov;
    }
}

extern "C" void kernel_launch(void* const* d_in, const int* in_sizes, int n_in,
                              void* d_out, int out_size, void* d_ws, size_t ws_size,
                              hipStream_t stream)
{
    (void)in_sizes; (void)n_in; (void)out_size; (void)ws_size;
    const float* x  = (const float*)d_in[0];
    const float* Wq = (const float*)d_in[1];
    const float* bq = (const float*)d_in[2];
    const float* Wk = (const float*)d_in[3];
    const float* bk = (const float*)d_in[4];
    const float* Wv = (const float*)d_in[5];
    const float* bv = (const float*)d_in[6];
    const float* gm = (const float*)d_in[7];
    float* out = (float*)d_out;

    ushort* qw = (ushort*)d_ws;
    ushort* kw = qw + (size_t)BATCH * NPIX * DQKD;
    ushort* vw = kw + (size_t)BATCH * NPIX * DQKD;

    dim3 g1(NPIX / 256, 10, BATCH);
    proj_kernel<<<g1, 256, 0, stream>>>(x, Wq, bq, Wk, bk, Wv, bv, qw, kw, vw);

    attn_kernel<<<dim3(512), 512, 0, stream>>>(qw, kw, vw, x, gm, out);
}